// Round 5
// baseline (3702.073 us; speedup 1.0000x reference)
//
#include <hip/hip_runtime.h>
#include <math.h>

#define CDIM 256
#define NHEAD 8
#define HD 32
#define BSZ 8
#define NTOK 256
#define MROWS (BSZ*NTOK)   // 2048
#define LN_EPS 1e-5f
#define DT_STEP 0.01f

// ---------------------------------------------------------------------------
// LayerNorm statistics across 256 threads (one column each) for R rows.
// (used by oproj kernel only)
// ---------------------------------------------------------------------------
template<int R>
__device__ __forceinline__ void ln_stats(const float* val, int tid,
        float (*part_s)[R], float (*part_q)[R], float* mb, float* rb) {
    const int lane = tid & 63;
    const int wid  = tid >> 6;
    #pragma unroll
    for (int r = 0; r < R; ++r) {
        float s = val[r];
        float q = val[r] * val[r];
        #pragma unroll
        for (int off = 32; off > 0; off >>= 1) {
            s += __shfl_down(s, off, 64);
            q += __shfl_down(q, off, 64);
        }
        if (lane == 0) { part_s[wid][r] = s; part_q[wid][r] = q; }
    }
    __syncthreads();
    if (tid < R) {
        float S = part_s[0][tid] + part_s[1][tid] + part_s[2][tid] + part_s[3][tid];
        float Q = part_q[0][tid] + part_q[1][tid] + part_q[2][tid] + part_q[3][tid];
        float mean = S * (1.0f / CDIM);
        float var  = Q * (1.0f / CDIM) - mean * mean;
        mb[tid] = mean;
        rb[tid] = rsqrtf(var + LN_EPS);
    }
    __syncthreads();
}

// ---------------------------------------------------------------------------
// QKV projection: OUT[M][768] = X[M][256] @ W[256][768] + bias
// ---------------------------------------------------------------------------
__global__ __launch_bounds__(256) void qkv_kernel(
        const float* __restrict__ X, const float* __restrict__ W,
        const float* __restrict__ bias, float* __restrict__ OUT) {
    const int R = 8;
    __shared__ float xs[R][CDIM];
    const int base = blockIdx.x * R;
    const int tid = threadIdx.x;
    #pragma unroll
    for (int r = 0; r < R; ++r) xs[r][tid] = X[(size_t)(base + r) * CDIM + tid];
    __syncthreads();
    for (int g = 0; g < 3; ++g) {
        const int j = g * 256 + tid;
        float acc[R];
        #pragma unroll
        for (int r = 0; r < R; ++r) acc[r] = 0.0f;
        const float* wp = W + j;
        for (int k = 0; k < CDIM; k += 4) {
            float w0 = wp[(size_t)(k+0)*768];
            float w1 = wp[(size_t)(k+1)*768];
            float w2 = wp[(size_t)(k+2)*768];
            float w3 = wp[(size_t)(k+3)*768];
            #pragma unroll
            for (int r = 0; r < R; ++r) {
                float4 xv = *reinterpret_cast<const float4*>(&xs[r][k]);
                acc[r] = fmaf(xv.x, w0, acc[r]);
                acc[r] = fmaf(xv.y, w1, acc[r]);
                acc[r] = fmaf(xv.z, w2, acc[r]);
                acc[r] = fmaf(xv.w, w3, acc[r]);
            }
        }
        const float bb = bias[j];
        #pragma unroll
        for (int r = 0; r < R; ++r) OUT[(size_t)(base + r) * 768 + j] = acc[r] + bb;
    }
}

// ---------------------------------------------------------------------------
// Per-(b,h) attention with online softmax. One WG per (b,h); thread = query row.
// ---------------------------------------------------------------------------
__global__ __launch_bounds__(256) void attn_kernel(
        const float* __restrict__ QKV, float* __restrict__ PO) {
    __shared__ float ks[NTOK][HD];
    __shared__ float vs[NTOK][HD];
    const int bh = blockIdx.x;
    const int b = bh >> 3;
    const int h = bh & 7;
    const int tid = threadIdx.x;
    for (int idx = tid; idx < NTOK * HD; idx += 256) {
        const int j = idx >> 5;
        const int d = idx & 31;
        const float* row = QKV + (size_t)(b * NTOK + j) * 768 + h * HD + d;
        ks[j][d] = row[256];
        vs[j][d] = row[512];
    }
    __syncthreads();
    float q[HD];
    const float* qrow = QKV + (size_t)(b * NTOK + tid) * 768 + h * HD;
    #pragma unroll
    for (int d = 0; d < HD; ++d) q[d] = qrow[d];
    const float scale = 0.17677669529663687f;   // 1/sqrt(32)
    float m = -1e30f, l = 0.0f;
    float po[HD];
    #pragma unroll
    for (int d = 0; d < HD; ++d) po[d] = 0.0f;
    for (int j = 0; j < NTOK; ++j) {
        float s = 0.0f;
        #pragma unroll
        for (int d = 0; d < HD; ++d) s = fmaf(q[d], ks[j][d], s);
        s *= scale;
        const float nm = fmaxf(m, s);
        const float corr = __expf(m - nm);
        const float p = __expf(s - nm);
        l = l * corr + p;
        #pragma unroll
        for (int d = 0; d < HD; ++d) po[d] = fmaf(po[d], corr, p * vs[j][d]);
        m = nm;
    }
    const float inv = 1.0f / l;
    float* dst = PO + (size_t)(b * NTOK + tid) * CDIM + h * HD;
    #pragma unroll
    for (int d = 0; d < HD; ++d) dst[d] = po[d] * inv;
}

// ---------------------------------------------------------------------------
// Out-proj + bias + residual(x) + LayerNorm(g1,b1) -> X1
// ---------------------------------------------------------------------------
__global__ __launch_bounds__(256) void oproj_ln_kernel(
        const float* __restrict__ PO, const float* __restrict__ WO,
        const float* __restrict__ BO, const float* __restrict__ X,
        const float* __restrict__ G1, const float* __restrict__ B1,
        float* __restrict__ X1) {
    const int R = 8;
    __shared__ float ps[R][CDIM];
    __shared__ float part_s[4][R], part_q[4][R];
    __shared__ float mb[R], rb[R];
    const int base = blockIdx.x * R;
    const int tid = threadIdx.x;
    #pragma unroll
    for (int r = 0; r < R; ++r) ps[r][tid] = PO[(size_t)(base + r) * CDIM + tid];
    __syncthreads();
    float acc[R];
    #pragma unroll
    for (int r = 0; r < R; ++r) acc[r] = 0.0f;
    const float* wp = WO + tid;
    for (int k = 0; k < CDIM; k += 4) {
        float w0 = wp[(size_t)(k+0)*CDIM];
        float w1 = wp[(size_t)(k+1)*CDIM];
        float w2 = wp[(size_t)(k+2)*CDIM];
        float w3 = wp[(size_t)(k+3)*CDIM];
        #pragma unroll
        for (int r = 0; r < R; ++r) {
            float4 xv = *reinterpret_cast<const float4*>(&ps[r][k]);
            acc[r] = fmaf(xv.x, w0, acc[r]);
            acc[r] = fmaf(xv.y, w1, acc[r]);
            acc[r] = fmaf(xv.z, w2, acc[r]);
            acc[r] = fmaf(xv.w, w3, acc[r]);
        }
    }
    const float bo = BO[tid];
    float val[R];
    #pragma unroll
    for (int r = 0; r < R; ++r)
        val[r] = acc[r] + bo + X[(size_t)(base + r) * CDIM + tid];
    ln_stats<R>(val, tid, part_s, part_q, mb, rb);
    const float g = G1[tid], bb = B1[tid];
    #pragma unroll
    for (int r = 0; r < R; ++r)
        X1[(size_t)(base + r) * CDIM + tid] = (val[r] - mb[r]) * rb[r] * g + bb;
}

// ---------------------------------------------------------------------------
// Persistent ODE kernel — packed-bf16 weights-in-registers edition.
// Block = 1024 threads (16 waves, hard cap 128 VGPR/wave).  thread t:
//   col = t&255, kq = t>>8.  Weight slice WL1/WL2[64k x 1col] held as
//   32+32 packed-bf16 u32 VGPRs (RNE), unpacked to f32 in the inner loop.
// All arithmetic/activations remain f32; in-loop memory traffic is LDS only.
// ---------------------------------------------------------------------------
struct OdeShared {
    float bufA[8][CDIM];     // feval arg
    float bufB[8][CDIM];     // relu(h)
    float red[4][8][CDIM];   // k-partials
    float pS[16][2], pQ[16][2];
};

__device__ __forceinline__ unsigned int bf16_rne(float x) {
    unsigned int u = __float_as_uint(x);
    return (u + 0x7FFFu + ((u >> 16) & 1u)) >> 16;
}

// k-sliced GEMV with packed-bf16 weights: acc[0..7] += buf[r][k0+kk]*w[kk]
__device__ __forceinline__ void gemv_slice_p(
        const float (*buf)[CDIM], int k0, const unsigned int* wp, float* acc) {
    #pragma unroll
    for (int kk = 0; kk < 64; kk += 4) {
        const unsigned int p0 = wp[(kk >> 1) + 0];   // weights kk, kk+1
        const unsigned int p1 = wp[(kk >> 1) + 1];   // weights kk+2, kk+3
        const float w0 = __uint_as_float(p0 << 16);
        const float w1 = __uint_as_float(p0 & 0xFFFF0000u);
        const float w2 = __uint_as_float(p1 << 16);
        const float w3 = __uint_as_float(p1 & 0xFFFF0000u);
        #pragma unroll
        for (int r = 0; r < 8; ++r) {
            float4 xv = *reinterpret_cast<const float4*>(&buf[r][k0 + kk]);
            acc[r] = fmaf(xv.x, w0, acc[r]);
            acc[r] = fmaf(xv.y, w1, acc[r]);
            acc[r] = fmaf(xv.z, w2, acc[r]);
            acc[r] = fmaf(xv.w, w3, acc[r]);
        }
    }
}

__device__ __forceinline__ void ode_feval(
        float a0, float a1, float& o0, float& o1,
        int col, int kq, int lane, int wid,
        const unsigned int* w1p, const unsigned int* w2p,
        float bl1, float bl2, float gnv, float bnv, OdeShared& sh) {
    const int r0 = kq * 2;
    const int k0 = kq * 64;
    sh.bufA[r0][col]     = a0;
    sh.bufA[r0 + 1][col] = a1;
    __syncthreads();

    // ---- GEMV1 partial (weights in regs, activations via LDS broadcast)
    float acc[8];
    #pragma unroll
    for (int r = 0; r < 8; ++r) acc[r] = 0.0f;
    gemv_slice_p(sh.bufA, k0, w1p, acc);
    #pragma unroll
    for (int r = 0; r < 8; ++r) sh.red[kq][r][col] = acc[r];
    __syncthreads();

    // ---- owner reduces its 2 rows, applies bias+relu, stages bufB
    {
        float h0 = sh.red[0][r0][col] + sh.red[1][r0][col]
                 + sh.red[2][r0][col] + sh.red[3][r0][col] + bl1;
        float h1 = sh.red[0][r0+1][col] + sh.red[1][r0+1][col]
                 + sh.red[2][r0+1][col] + sh.red[3][r0+1][col] + bl1;
        sh.bufB[r0][col]     = fmaxf(h0, 0.0f);
        sh.bufB[r0 + 1][col] = fmaxf(h1, 0.0f);
    }
    __syncthreads();

    // ---- GEMV2 partial
    #pragma unroll
    for (int r = 0; r < 8; ++r) acc[r] = 0.0f;
    gemv_slice_p(sh.bufB, k0, w2p, acc);
    #pragma unroll
    for (int r = 0; r < 8; ++r) sh.red[kq][r][col] = acc[r];
    __syncthreads();

    // ---- owner: v = gemv2 + bl2 + arg, then LayerNorm(gn,bn)
    float v0 = sh.red[0][r0][col] + sh.red[1][r0][col]
             + sh.red[2][r0][col] + sh.red[3][r0][col] + bl2 + a0;
    float v1 = sh.red[0][r0+1][col] + sh.red[1][r0+1][col]
             + sh.red[2][r0+1][col] + sh.red[3][r0+1][col] + bl2 + a1;

    float s0 = v0, q0 = v0 * v0, s1 = v1, q1 = v1 * v1;
    #pragma unroll
    for (int off = 32; off > 0; off >>= 1) {
        s0 += __shfl_down(s0, off, 64);
        q0 += __shfl_down(q0, off, 64);
        s1 += __shfl_down(s1, off, 64);
        q1 += __shfl_down(q1, off, 64);
    }
    if (lane == 0) {
        sh.pS[wid][0] = s0; sh.pQ[wid][0] = q0;
        sh.pS[wid][1] = s1; sh.pQ[wid][1] = q1;
    }
    __syncthreads();
    const int wb = kq << 2;
    float S0 = sh.pS[wb][0] + sh.pS[wb+1][0] + sh.pS[wb+2][0] + sh.pS[wb+3][0];
    float Q0 = sh.pQ[wb][0] + sh.pQ[wb+1][0] + sh.pQ[wb+2][0] + sh.pQ[wb+3][0];
    float S1 = sh.pS[wb][1] + sh.pS[wb+1][1] + sh.pS[wb+2][1] + sh.pS[wb+3][1];
    float Q1 = sh.pQ[wb][1] + sh.pQ[wb+1][1] + sh.pQ[wb+2][1] + sh.pQ[wb+3][1];
    float m0 = S0 * (1.0f / CDIM);
    float m1 = S1 * (1.0f / CDIM);
    float rs0 = rsqrtf(Q0 * (1.0f / CDIM) - m0 * m0 + LN_EPS);
    float rs1 = rsqrtf(Q1 * (1.0f / CDIM) - m1 * m1 + LN_EPS);
    o0 = (v0 - m0) * rs0 * gnv + bnv;
    o1 = (v1 - m1) * rs1 * gnv + bnv;
}

__global__ __launch_bounds__(1024) void ode_kernel(
        const float* __restrict__ X1,
        const float* __restrict__ WL1, const float* __restrict__ BL1,
        const float* __restrict__ WL2, const float* __restrict__ BL2,
        const float* __restrict__ GN, const float* __restrict__ BN,
        const float* __restrict__ G2, const float* __restrict__ B2,
        const int* __restrict__ LT, const int* __restrict__ NSTEP,
        float* __restrict__ OUT) {
    __shared__ OdeShared sh;
    const int t = threadIdx.x;
    const int col = t & 255;
    const int kq  = t >> 8;         // k-quarter == row-pair owner id
    const int lane = t & 63;
    const int wid  = t >> 6;
    const int wg = blockIdx.x;
    const int b  = wg >> 5;
    const int rg = wg & 31;
    const int base = b * NTOK + rg * 8;
    int steps = LT[b];
    const int ns = NSTEP[0];
    if (steps > ns) steps = ns;

    const float bl1 = BL1[col], bl2 = BL2[col];
    const float gnv = GN[col],  bnv = BN[col];
    const int k0 = kq * 64;

    // ---- one-time weight preload: pack 2 bf16(RNE) per u32 VGPR
    unsigned int w1p[32], w2p[32];
    {
        const float* p1 = WL1 + (size_t)k0 * CDIM + col;
        const float* p2 = WL2 + (size_t)k0 * CDIM + col;
        #pragma unroll
        for (int j = 0; j < 32; ++j) {
            float a1w = p1[(size_t)(2*j)   * CDIM];
            float b1w = p1[(size_t)(2*j+1) * CDIM];
            float a2w = p2[(size_t)(2*j)   * CDIM];
            float b2w = p2[(size_t)(2*j+1) * CDIM];
            w1p[j] = bf16_rne(a1w) | (bf16_rne(b1w) << 16);
            w2p[j] = bf16_rne(a2w) | (bf16_rne(b2w) << 16);
        }
    }

    const int r0 = kq * 2;
    const float x10 = X1[(size_t)(base + r0) * CDIM + col];
    const float x11 = X1[(size_t)(base + r0 + 1) * CDIM + col];
    float y0 = x10, y1 = x11;

    for (int s = 0; s < steps; ++s) {
        float k10, k11, k20, k21, k30, k31, k40, k41, a0, a1;
        ode_feval(y0, y1, k10, k11, col, kq, lane, wid, w1p, w2p, bl1, bl2, gnv, bnv, sh);
        a0 = fmaf(DT_STEP * (1.0f/3.0f), k10, y0);
        a1 = fmaf(DT_STEP * (1.0f/3.0f), k11, y1);
        ode_feval(a0, a1, k20, k21, col, kq, lane, wid, w1p, w2p, bl1, bl2, gnv, bnv, sh);
        a0 = fmaf(DT_STEP, k20 - k10 * (1.0f/3.0f), y0);
        a1 = fmaf(DT_STEP, k21 - k11 * (1.0f/3.0f), y1);
        ode_feval(a0, a1, k30, k31, col, kq, lane, wid, w1p, w2p, bl1, bl2, gnv, bnv, sh);
        a0 = fmaf(DT_STEP, k10 - k20 + k30, y0);
        a1 = fmaf(DT_STEP, k11 - k21 + k31, y1);
        ode_feval(a0, a1, k40, k41, col, kq, lane, wid, w1p, w2p, bl1, bl2, gnv, bnv, sh);
        y0 = fmaf(DT_STEP * 0.125f, k10 + 3.0f * (k20 + k30) + k40, y0);
        y1 = fmaf(DT_STEP * 0.125f, k11 + 3.0f * (k21 + k31) + k41, y1);
    }

    // ---- final: OUT = LN(x1 + y, g2, b2)
    float v0 = x10 + y0;
    float v1 = x11 + y1;
    float s0 = v0, q0 = v0 * v0, s1 = v1, q1 = v1 * v1;
    #pragma unroll
    for (int off = 32; off > 0; off >>= 1) {
        s0 += __shfl_down(s0, off, 64);
        q0 += __shfl_down(q0, off, 64);
        s1 += __shfl_down(s1, off, 64);
        q1 += __shfl_down(q1, off, 64);
    }
    if (lane == 0) {
        sh.pS[wid][0] = s0; sh.pQ[wid][0] = q0;
        sh.pS[wid][1] = s1; sh.pQ[wid][1] = q1;
    }
    __syncthreads();
    const int wb = kq << 2;
    float S0 = sh.pS[wb][0] + sh.pS[wb+1][0] + sh.pS[wb+2][0] + sh.pS[wb+3][0];
    float Q0 = sh.pQ[wb][0] + sh.pQ[wb+1][0] + sh.pQ[wb+2][0] + sh.pQ[wb+3][0];
    float S1 = sh.pS[wb][1] + sh.pS[wb+1][1] + sh.pS[wb+2][1] + sh.pS[wb+3][1];
    float Q1 = sh.pQ[wb][1] + sh.pQ[wb+1][1] + sh.pQ[wb+2][1] + sh.pQ[wb+3][1];
    float m0 = S0 * (1.0f / CDIM);
    float m1 = S1 * (1.0f / CDIM);
    float rs0 = rsqrtf(Q0 * (1.0f / CDIM) - m0 * m0 + LN_EPS);
    float rs1 = rsqrtf(Q1 * (1.0f / CDIM) - m1 * m1 + LN_EPS);
    const float g2 = G2[col], b2 = B2[col];
    OUT[(size_t)(base + r0) * CDIM + col]     = (v0 - m0) * rs0 * g2 + b2;
    OUT[(size_t)(base + r0 + 1) * CDIM + col] = (v1 - m1) * rs1 * g2 + b2;
}

// ---------------------------------------------------------------------------
extern "C" void kernel_launch(void* const* d_in, const int* in_sizes, int n_in,
                              void* d_out, int out_size, void* d_ws, size_t ws_size,
                              hipStream_t stream) {
    const float* x    = (const float*)d_in[0];
    const float* wqkv = (const float*)d_in[1];
    const float* bqkv = (const float*)d_in[2];
    const float* wo   = (const float*)d_in[3];
    const float* bo   = (const float*)d_in[4];
    const float* g1   = (const float*)d_in[5];
    const float* b1   = (const float*)d_in[6];
    const float* g2   = (const float*)d_in[7];
    const float* b2   = (const float*)d_in[8];
    const float* wl1  = (const float*)d_in[9];
    const float* bl1  = (const float*)d_in[10];
    const float* wl2  = (const float*)d_in[11];
    const float* bl2  = (const float*)d_in[12];
    const float* gn   = (const float*)d_in[13];
    const float* bn   = (const float*)d_in[14];
    const int*   lt   = (const int*)d_in[15];
    const int*   nst  = (const int*)d_in[16];

    float* ws  = (float*)d_ws;
    float* qkv = ws;                              // M*768
    float* po  = qkv + (size_t)MROWS * 768;       // M*256
    float* x1  = po  + (size_t)MROWS * CDIM;      // M*256
    float* out = (float*)d_out;

    hipLaunchKernelGGL(qkv_kernel, dim3(MROWS / 8), dim3(256), 0, stream,
                       x, wqkv, bqkv, qkv);
    hipLaunchKernelGGL(attn_kernel, dim3(BSZ * NHEAD), dim3(256), 0, stream,
                       qkv, po);
    hipLaunchKernelGGL(oproj_ln_kernel, dim3(MROWS / 8), dim3(256), 0, stream,
                       po, wo, bo, x, g1, b1, x1);
    hipLaunchKernelGGL(ode_kernel, dim3(MROWS / 8), dim3(1024), 0, stream,
                       x1, wl1, bl1, wl2, bl2, gn, bn, g2, b2, lt, nst, out);
}

// Round 6
// 3416.007 us; speedup vs baseline: 1.0837x; 1.0837x over previous
//
#include <hip/hip_runtime.h>
#include <math.h>

#define CDIM 256
#define NHEAD 8
#define HD 32
#define BSZ 8
#define NTOK 256
#define MROWS (BSZ*NTOK)   // 2048
#define LN_EPS 1e-5f
#define DT_STEP 0.01f

// ---------------------------------------------------------------------------
// LayerNorm statistics across 256 threads (one column each) for R rows.
// (used by oproj kernel only)
// ---------------------------------------------------------------------------
template<int R>
__device__ __forceinline__ void ln_stats(const float* val, int tid,
        float (*part_s)[R], float (*part_q)[R], float* mb, float* rb) {
    const int lane = tid & 63;
    const int wid  = tid >> 6;
    #pragma unroll
    for (int r = 0; r < R; ++r) {
        float s = val[r];
        float q = val[r] * val[r];
        #pragma unroll
        for (int off = 32; off > 0; off >>= 1) {
            s += __shfl_down(s, off, 64);
            q += __shfl_down(q, off, 64);
        }
        if (lane == 0) { part_s[wid][r] = s; part_q[wid][r] = q; }
    }
    __syncthreads();
    if (tid < R) {
        float S = part_s[0][tid] + part_s[1][tid] + part_s[2][tid] + part_s[3][tid];
        float Q = part_q[0][tid] + part_q[1][tid] + part_q[2][tid] + part_q[3][tid];
        float mean = S * (1.0f / CDIM);
        float var  = Q * (1.0f / CDIM) - mean * mean;
        mb[tid] = mean;
        rb[tid] = rsqrtf(var + LN_EPS);
    }
    __syncthreads();
}

// ---------------------------------------------------------------------------
// QKV projection: OUT[M][768] = X[M][256] @ W[256][768] + bias
// ---------------------------------------------------------------------------
__global__ __launch_bounds__(256) void qkv_kernel(
        const float* __restrict__ X, const float* __restrict__ W,
        const float* __restrict__ bias, float* __restrict__ OUT) {
    const int R = 8;
    __shared__ float xs[R][CDIM];
    const int base = blockIdx.x * R;
    const int tid = threadIdx.x;
    #pragma unroll
    for (int r = 0; r < R; ++r) xs[r][tid] = X[(size_t)(base + r) * CDIM + tid];
    __syncthreads();
    for (int g = 0; g < 3; ++g) {
        const int j = g * 256 + tid;
        float acc[R];
        #pragma unroll
        for (int r = 0; r < R; ++r) acc[r] = 0.0f;
        const float* wp = W + j;
        for (int k = 0; k < CDIM; k += 4) {
            float w0 = wp[(size_t)(k+0)*768];
            float w1 = wp[(size_t)(k+1)*768];
            float w2 = wp[(size_t)(k+2)*768];
            float w3 = wp[(size_t)(k+3)*768];
            #pragma unroll
            for (int r = 0; r < R; ++r) {
                float4 xv = *reinterpret_cast<const float4*>(&xs[r][k]);
                acc[r] = fmaf(xv.x, w0, acc[r]);
                acc[r] = fmaf(xv.y, w1, acc[r]);
                acc[r] = fmaf(xv.z, w2, acc[r]);
                acc[r] = fmaf(xv.w, w3, acc[r]);
            }
        }
        const float bb = bias[j];
        #pragma unroll
        for (int r = 0; r < R; ++r) OUT[(size_t)(base + r) * 768 + j] = acc[r] + bb;
    }
}

// ---------------------------------------------------------------------------
// Per-(b,h) attention with online softmax. One WG per (b,h); thread = query row.
// ---------------------------------------------------------------------------
__global__ __launch_bounds__(256) void attn_kernel(
        const float* __restrict__ QKV, float* __restrict__ PO) {
    __shared__ float ks[NTOK][HD];
    __shared__ float vs[NTOK][HD];
    const int bh = blockIdx.x;
    const int b = bh >> 3;
    const int h = bh & 7;
    const int tid = threadIdx.x;
    for (int idx = tid; idx < NTOK * HD; idx += 256) {
        const int j = idx >> 5;
        const int d = idx & 31;
        const float* row = QKV + (size_t)(b * NTOK + j) * 768 + h * HD + d;
        ks[j][d] = row[256];
        vs[j][d] = row[512];
    }
    __syncthreads();
    float q[HD];
    const float* qrow = QKV + (size_t)(b * NTOK + tid) * 768 + h * HD;
    #pragma unroll
    for (int d = 0; d < HD; ++d) q[d] = qrow[d];
    const float scale = 0.17677669529663687f;   // 1/sqrt(32)
    float m = -1e30f, l = 0.0f;
    float po[HD];
    #pragma unroll
    for (int d = 0; d < HD; ++d) po[d] = 0.0f;
    for (int j = 0; j < NTOK; ++j) {
        float s = 0.0f;
        #pragma unroll
        for (int d = 0; d < HD; ++d) s = fmaf(q[d], ks[j][d], s);
        s *= scale;
        const float nm = fmaxf(m, s);
        const float corr = __expf(m - nm);
        const float p = __expf(s - nm);
        l = l * corr + p;
        #pragma unroll
        for (int d = 0; d < HD; ++d) po[d] = fmaf(po[d], corr, p * vs[j][d]);
        m = nm;
    }
    const float inv = 1.0f / l;
    float* dst = PO + (size_t)(b * NTOK + tid) * CDIM + h * HD;
    #pragma unroll
    for (int d = 0; d < HD; ++d) dst[d] = po[d] * inv;
}

// ---------------------------------------------------------------------------
// Out-proj + bias + residual(x) + LayerNorm(g1,b1) -> X1
// ---------------------------------------------------------------------------
__global__ __launch_bounds__(256) void oproj_ln_kernel(
        const float* __restrict__ PO, const float* __restrict__ WO,
        const float* __restrict__ BO, const float* __restrict__ X,
        const float* __restrict__ G1, const float* __restrict__ B1,
        float* __restrict__ X1) {
    const int R = 8;
    __shared__ float ps[R][CDIM];
    __shared__ float part_s[4][R], part_q[4][R];
    __shared__ float mb[R], rb[R];
    const int base = blockIdx.x * R;
    const int tid = threadIdx.x;
    #pragma unroll
    for (int r = 0; r < R; ++r) ps[r][tid] = PO[(size_t)(base + r) * CDIM + tid];
    __syncthreads();
    float acc[R];
    #pragma unroll
    for (int r = 0; r < R; ++r) acc[r] = 0.0f;
    const float* wp = WO + tid;
    for (int k = 0; k < CDIM; k += 4) {
        float w0 = wp[(size_t)(k+0)*CDIM];
        float w1 = wp[(size_t)(k+1)*CDIM];
        float w2 = wp[(size_t)(k+2)*CDIM];
        float w3 = wp[(size_t)(k+3)*CDIM];
        #pragma unroll
        for (int r = 0; r < R; ++r) {
            float4 xv = *reinterpret_cast<const float4*>(&ps[r][k]);
            acc[r] = fmaf(xv.x, w0, acc[r]);
            acc[r] = fmaf(xv.y, w1, acc[r]);
            acc[r] = fmaf(xv.z, w2, acc[r]);
            acc[r] = fmaf(xv.w, w3, acc[r]);
        }
    }
    const float bo = BO[tid];
    float val[R];
    #pragma unroll
    for (int r = 0; r < R; ++r)
        val[r] = acc[r] + bo + X[(size_t)(base + r) * CDIM + tid];
    ln_stats<R>(val, tid, part_s, part_q, mb, rb);
    const float g = G1[tid], bb = B1[tid];
    #pragma unroll
    for (int r = 0; r < R; ++r)
        X1[(size_t)(base + r) * CDIM + tid] = (val[r] - mb[r]) * rb[r] * g + bb;
}

// ---------------------------------------------------------------------------
// Persistent ODE kernel — packed-bf16 weights-in-registers, occupancy-pinned.
// __launch_bounds__(1024, 4): 1024-thread block = 16 waves = 4 waves/EU when
// exactly one block is resident; declaring min 4 waves/EU gives the register
// allocator a 128-VGPR budget (vs the 64-VGPR cap it picked from the LDS-based
// 8-waves/EU occupancy heuristic — which spilled the weight arrays to scratch
// in rounds 3/5: VGPR_Count=64, WRITE_SIZE 840 MB).
// Weights: uint4 w1v[8]/w2v[8] = 64 VGPRs, 2 bf16 per u32, all indices static.
// ---------------------------------------------------------------------------
struct OdeShared {
    float bufA[8][CDIM];     // feval arg
    float bufB[8][CDIM];     // relu(h)
    float red[4][8][CDIM];   // k-partials
    float pS[16][2], pQ[16][2];
};

__device__ __forceinline__ unsigned int bf16_rne(float x) {
    unsigned int u = __float_as_uint(x);
    return (u + 0x7FFFu + ((u >> 16) & 1u)) >> 16;
}

// k-sliced GEMV with packed-bf16 weights held in uint4 regs.
// acc[0..7] += sum over my 64 k of buf[r][k0+k] * w[k]
__device__ __forceinline__ void gemv_slice_p(
        const float (*buf)[CDIM], int k0, const uint4* wv, float* acc) {
    #pragma unroll
    for (int c = 0; c < 8; ++c) {          // uint4 c covers k = 8c .. 8c+7
        const uint4 pv = wv[c];
        const float w0 = __uint_as_float(pv.x << 16);
        const float w1 = __uint_as_float(pv.x & 0xFFFF0000u);
        const float w2 = __uint_as_float(pv.y << 16);
        const float w3 = __uint_as_float(pv.y & 0xFFFF0000u);
        const float w4 = __uint_as_float(pv.z << 16);
        const float w5 = __uint_as_float(pv.z & 0xFFFF0000u);
        const float w6 = __uint_as_float(pv.w << 16);
        const float w7 = __uint_as_float(pv.w & 0xFFFF0000u);
        #pragma unroll
        for (int r = 0; r < 8; ++r) {
            const float4 x0 = *reinterpret_cast<const float4*>(&buf[r][k0 + 8*c]);
            const float4 x1 = *reinterpret_cast<const float4*>(&buf[r][k0 + 8*c + 4]);
            acc[r] = fmaf(x0.x, w0, acc[r]);
            acc[r] = fmaf(x0.y, w1, acc[r]);
            acc[r] = fmaf(x0.z, w2, acc[r]);
            acc[r] = fmaf(x0.w, w3, acc[r]);
            acc[r] = fmaf(x1.x, w4, acc[r]);
            acc[r] = fmaf(x1.y, w5, acc[r]);
            acc[r] = fmaf(x1.z, w6, acc[r]);
            acc[r] = fmaf(x1.w, w7, acc[r]);
        }
    }
}

__device__ __forceinline__ void ode_feval(
        float a0, float a1, float& o0, float& o1,
        int col, int kq, int lane, int wid,
        const uint4* w1v, const uint4* w2v,
        float bl1, float bl2, float gnv, float bnv, OdeShared& sh) {
    const int r0 = kq * 2;
    const int k0 = kq * 64;
    sh.bufA[r0][col]     = a0;
    sh.bufA[r0 + 1][col] = a1;
    __syncthreads();

    // ---- GEMV1 partial (weights in regs, activations via LDS broadcast)
    float acc[8];
    #pragma unroll
    for (int r = 0; r < 8; ++r) acc[r] = 0.0f;
    gemv_slice_p(sh.bufA, k0, w1v, acc);
    #pragma unroll
    for (int r = 0; r < 8; ++r) sh.red[kq][r][col] = acc[r];
    __syncthreads();

    // ---- owner reduces its 2 rows, applies bias+relu, stages bufB
    {
        float h0 = sh.red[0][r0][col] + sh.red[1][r0][col]
                 + sh.red[2][r0][col] + sh.red[3][r0][col] + bl1;
        float h1 = sh.red[0][r0+1][col] + sh.red[1][r0+1][col]
                 + sh.red[2][r0+1][col] + sh.red[3][r0+1][col] + bl1;
        sh.bufB[r0][col]     = fmaxf(h0, 0.0f);
        sh.bufB[r0 + 1][col] = fmaxf(h1, 0.0f);
    }
    __syncthreads();

    // ---- GEMV2 partial
    #pragma unroll
    for (int r = 0; r < 8; ++r) acc[r] = 0.0f;
    gemv_slice_p(sh.bufB, k0, w2v, acc);
    #pragma unroll
    for (int r = 0; r < 8; ++r) sh.red[kq][r][col] = acc[r];
    __syncthreads();

    // ---- owner: v = gemv2 + bl2 + arg, then LayerNorm(gn,bn)
    float v0 = sh.red[0][r0][col] + sh.red[1][r0][col]
             + sh.red[2][r0][col] + sh.red[3][r0][col] + bl2 + a0;
    float v1 = sh.red[0][r0+1][col] + sh.red[1][r0+1][col]
             + sh.red[2][r0+1][col] + sh.red[3][r0+1][col] + bl2 + a1;

    float s0 = v0, q0 = v0 * v0, s1 = v1, q1 = v1 * v1;
    #pragma unroll
    for (int off = 32; off > 0; off >>= 1) {
        s0 += __shfl_down(s0, off, 64);
        q0 += __shfl_down(q0, off, 64);
        s1 += __shfl_down(s1, off, 64);
        q1 += __shfl_down(q1, off, 64);
    }
    if (lane == 0) {
        sh.pS[wid][0] = s0; sh.pQ[wid][0] = q0;
        sh.pS[wid][1] = s1; sh.pQ[wid][1] = q1;
    }
    __syncthreads();
    const int wb = kq << 2;
    float S0 = sh.pS[wb][0] + sh.pS[wb+1][0] + sh.pS[wb+2][0] + sh.pS[wb+3][0];
    float Q0 = sh.pQ[wb][0] + sh.pQ[wb+1][0] + sh.pQ[wb+2][0] + sh.pQ[wb+3][0];
    float S1 = sh.pS[wb][1] + sh.pS[wb+1][1] + sh.pS[wb+2][1] + sh.pS[wb+3][1];
    float Q1 = sh.pQ[wb][1] + sh.pQ[wb+1][1] + sh.pQ[wb+2][1] + sh.pQ[wb+3][1];
    float m0 = S0 * (1.0f / CDIM);
    float m1 = S1 * (1.0f / CDIM);
    float rs0 = rsqrtf(Q0 * (1.0f / CDIM) - m0 * m0 + LN_EPS);
    float rs1 = rsqrtf(Q1 * (1.0f / CDIM) - m1 * m1 + LN_EPS);
    o0 = (v0 - m0) * rs0 * gnv + bnv;
    o1 = (v1 - m1) * rs1 * gnv + bnv;
}

__global__ __launch_bounds__(1024, 4) void ode_kernel(
        const float* __restrict__ X1,
        const float* __restrict__ WL1, const float* __restrict__ BL1,
        const float* __restrict__ WL2, const float* __restrict__ BL2,
        const float* __restrict__ GN, const float* __restrict__ BN,
        const float* __restrict__ G2, const float* __restrict__ B2,
        const int* __restrict__ LT, const int* __restrict__ NSTEP,
        float* __restrict__ OUT) {
    __shared__ OdeShared sh;
    const int t = threadIdx.x;
    const int col = t & 255;
    const int kq  = t >> 8;         // k-quarter == row-pair owner id
    const int lane = t & 63;
    const int wid  = t >> 6;
    const int wg = blockIdx.x;
    const int b  = wg >> 5;
    const int rg = wg & 31;
    const int base = b * NTOK + rg * 8;
    int steps = LT[b];
    const int ns = NSTEP[0];
    if (steps > ns) steps = ns;

    const float bl1 = BL1[col], bl2 = BL2[col];
    const float gnv = GN[col],  bnv = BN[col];
    const int k0 = kq * 64;

    // ---- one-time weight preload: pack 2 bf16(RNE) per u32, 4 u32 per uint4.
    // All indices compile-time constant so the arrays live in VGPRs.
    uint4 w1v[8], w2v[8];
    {
        const float* p1 = WL1 + (size_t)k0 * CDIM + col;
        const float* p2 = WL2 + (size_t)k0 * CDIM + col;
        #pragma unroll
        for (int c = 0; c < 8; ++c) {
            unsigned int u1[4], u2[4];
            #pragma unroll
            for (int q = 0; q < 4; ++q) {
                const int kk = 8 * c + 2 * q;
                float a1w = p1[(size_t)(kk)     * CDIM];
                float b1w = p1[(size_t)(kk + 1) * CDIM];
                float a2w = p2[(size_t)(kk)     * CDIM];
                float b2w = p2[(size_t)(kk + 1) * CDIM];
                u1[q] = bf16_rne(a1w) | (bf16_rne(b1w) << 16);
                u2[q] = bf16_rne(a2w) | (bf16_rne(b2w) << 16);
            }
            w1v[c] = make_uint4(u1[0], u1[1], u1[2], u1[3]);
            w2v[c] = make_uint4(u2[0], u2[1], u2[2], u2[3]);
        }
    }

    const int r0 = kq * 2;
    const float x10 = X1[(size_t)(base + r0) * CDIM + col];
    const float x11 = X1[(size_t)(base + r0 + 1) * CDIM + col];
    float y0 = x10, y1 = x11;

    for (int s = 0; s < steps; ++s) {
        float k10, k11, k20, k21, k30, k31, k40, k41, a0, a1;
        ode_feval(y0, y1, k10, k11, col, kq, lane, wid, w1v, w2v, bl1, bl2, gnv, bnv, sh);
        a0 = fmaf(DT_STEP * (1.0f/3.0f), k10, y0);
        a1 = fmaf(DT_STEP * (1.0f/3.0f), k11, y1);
        ode_feval(a0, a1, k20, k21, col, kq, lane, wid, w1v, w2v, bl1, bl2, gnv, bnv, sh);
        a0 = fmaf(DT_STEP, k20 - k10 * (1.0f/3.0f), y0);
        a1 = fmaf(DT_STEP, k21 - k11 * (1.0f/3.0f), y1);
        ode_feval(a0, a1, k30, k31, col, kq, lane, wid, w1v, w2v, bl1, bl2, gnv, bnv, sh);
        a0 = fmaf(DT_STEP, k10 - k20 + k30, y0);
        a1 = fmaf(DT_STEP, k11 - k21 + k31, y1);
        ode_feval(a0, a1, k40, k41, col, kq, lane, wid, w1v, w2v, bl1, bl2, gnv, bnv, sh);
        y0 = fmaf(DT_STEP * 0.125f, k10 + 3.0f * (k20 + k30) + k40, y0);
        y1 = fmaf(DT_STEP * 0.125f, k11 + 3.0f * (k21 + k31) + k41, y1);
    }

    // ---- final: OUT = LN(x1 + y, g2, b2)
    float v0 = x10 + y0;
    float v1 = x11 + y1;
    float s0 = v0, q0 = v0 * v0, s1 = v1, q1 = v1 * v1;
    #pragma unroll
    for (int off = 32; off > 0; off >>= 1) {
        s0 += __shfl_down(s0, off, 64);
        q0 += __shfl_down(q0, off, 64);
        s1 += __shfl_down(s1, off, 64);
        q1 += __shfl_down(q1, off, 64);
    }
    if (lane == 0) {
        sh.pS[wid][0] = s0; sh.pQ[wid][0] = q0;
        sh.pS[wid][1] = s1; sh.pQ[wid][1] = q1;
    }
    __syncthreads();
    const int wb = kq << 2;
    float S0 = sh.pS[wb][0] + sh.pS[wb+1][0] + sh.pS[wb+2][0] + sh.pS[wb+3][0];
    float Q0 = sh.pQ[wb][0] + sh.pQ[wb+1][0] + sh.pQ[wb+2][0] + sh.pQ[wb+3][0];
    float S1 = sh.pS[wb][1] + sh.pS[wb+1][1] + sh.pS[wb+2][1] + sh.pS[wb+3][1];
    float Q1 = sh.pQ[wb][1] + sh.pQ[wb+1][1] + sh.pQ[wb+2][1] + sh.pQ[wb+3][1];
    float m0 = S0 * (1.0f / CDIM);
    float m1 = S1 * (1.0f / CDIM);
    float rs0 = rsqrtf(Q0 * (1.0f / CDIM) - m0 * m0 + LN_EPS);
    float rs1 = rsqrtf(Q1 * (1.0f / CDIM) - m1 * m1 + LN_EPS);
    const float g2 = G2[col], b2 = B2[col];
    OUT[(size_t)(base + r0) * CDIM + col]     = (v0 - m0) * rs0 * g2 + b2;
    OUT[(size_t)(base + r0 + 1) * CDIM + col] = (v1 - m1) * rs1 * g2 + b2;
}

// ---------------------------------------------------------------------------
extern "C" void kernel_launch(void* const* d_in, const int* in_sizes, int n_in,
                              void* d_out, int out_size, void* d_ws, size_t ws_size,
                              hipStream_t stream) {
    const float* x    = (const float*)d_in[0];
    const float* wqkv = (const float*)d_in[1];
    const float* bqkv = (const float*)d_in[2];
    const float* wo   = (const float*)d_in[3];
    const float* bo   = (const float*)d_in[4];
    const float* g1   = (const float*)d_in[5];
    const float* b1   = (const float*)d_in[6];
    const float* g2   = (const float*)d_in[7];
    const float* b2   = (const float*)d_in[8];
    const float* wl1  = (const float*)d_in[9];
    const float* bl1  = (const float*)d_in[10];
    const float* wl2  = (const float*)d_in[11];
    const float* bl2  = (const float*)d_in[12];
    const float* gn   = (const float*)d_in[13];
    const float* bn   = (const float*)d_in[14];
    const int*   lt   = (const int*)d_in[15];
    const int*   nst  = (const int*)d_in[16];

    float* ws  = (float*)d_ws;
    float* qkv = ws;                              // M*768
    float* po  = qkv + (size_t)MROWS * 768;       // M*256
    float* x1  = po  + (size_t)MROWS * CDIM;      // M*256
    float* out = (float*)d_out;

    hipLaunchKernelGGL(qkv_kernel, dim3(MROWS / 8), dim3(256), 0, stream,
                       x, wqkv, bqkv, qkv);
    hipLaunchKernelGGL(attn_kernel, dim3(BSZ * NHEAD), dim3(256), 0, stream,
                       qkv, po);
    hipLaunchKernelGGL(oproj_ln_kernel, dim3(MROWS / 8), dim3(256), 0, stream,
                       po, wo, bo, x, g1, b1, x1);
    hipLaunchKernelGGL(ode_kernel, dim3(MROWS / 8), dim3(1024), 0, stream,
                       x1, wl1, bl1, wl2, bl2, gn, bn, g2, b2, lt, nst, out);
}